// Round 11
// baseline (195.878 us; speedup 1.0000x reference)
//
#include <hip/hip_runtime.h>
#include <hip/hip_bf16.h>

#define N1 8192
#define N2 8192
#define CDIM 128
#define HC 60
#define WC 80
#define HIMG 480
#define WIMG 640
#define NPIX (HC * WC)
#define INV_DENOM (1.0f / (8192.0f * 256.0f))
#define PADK 136            // LDS row stride (128 + 8 ushort): keeps 16B align
#define SEGU 48             // ushorts per (row, colblock) segment: cnt + 47 values
#define CAP 47              // mean 18.6, sigma 4.0; hot-row mean ~25 -> +5..7 sigma

using bf16x8 = __attribute__((ext_vector_type(8))) short;
using f32x4  = __attribute__((ext_vector_type(4))) float;

__device__ __forceinline__ ushort f2bf(float f) {
    union { float f; unsigned u; } x; x.f = f;
    unsigned u = x.u;
    unsigned r = (u + 0x7FFFu + ((u >> 16) & 1u)) >> 16;
    return (ushort)r;
}
__device__ __forceinline__ float bf2f(unsigned bits) {
    union { unsigned u; float f; } x; x.u = bits << 16; return x.f;
}
__device__ __forceinline__ unsigned key2bits(unsigned k) {
    return k ^ ((k & 0x8000u) ? 0x8000u : 0xFFFFu);
}
__device__ __forceinline__ unsigned bits2key(unsigned h) {
    return h ^ ((h & 0x8000u) ? 0xFFFFu : 0x8000u);
}

// ---------- prep: cvt A, cvt B to bf16 (R9 verbatim) ----------
__global__ void prep_kernel(const float* __restrict__ kp1d,
                            const float* __restrict__ kp2d,
                            ushort* __restrict__ Abf, ushort* __restrict__ Bbf) {
    const int n4 = N1 * CDIM / 4;        // 262144
    int i = blockIdx.x * blockDim.x + threadIdx.x;
    if (i < n4) {
        float4 v = ((const float4*)kp1d)[i];
        ushort4 o;
        o.x = f2bf(v.x); o.y = f2bf(v.y); o.z = f2bf(v.z); o.w = f2bf(v.w);
        ((ushort4*)Abf)[i] = o;
    } else if (i < 2 * n4) {
        int k = i - n4;
        float4 v = ((const float4*)kp2d)[k];
        ushort4 o;
        o.x = f2bf(v.x); o.y = f2bf(v.y); o.z = f2bf(v.z); o.w = f2bf(v.w);
        ((ushort4*)Bbf)[k] = o;
    }
}

// ---------- desc2 transpose with LDS tiling (R9 verbatim) ----------
__global__ void tr_kernel(const float* __restrict__ desc2, float* __restrict__ d2T) {
    __shared__ float tile[32][33];
    const int tx = threadIdx.x, ty = threadIdx.y;      // 32 x 8
    const int p0 = blockIdx.x * 32;
    const int c0 = blockIdx.y * 32;
    #pragma unroll
    for (int k = 0; k < 4; k++) {
        int c = c0 + ty + k * 8;
        tile[ty + k * 8][tx] = desc2[(size_t)c * NPIX + p0 + tx];
    }
    __syncthreads();
    #pragma unroll
    for (int k = 0; k < 4; k++) {
        int p = p0 + ty + k * 8;
        d2T[(size_t)p * CDIM + c0 + tx] = tile[tx][ty + k * 8];
    }
}

// ---------- positive term (R9 verbatim; R10's fusion was a measured loss) ----------
__global__ void pos_kernel(const float* __restrict__ wkp1,
                           const float* __restrict__ kp1d,
                           const float* __restrict__ desc2T,
                           float* __restrict__ ploss) {
    const int i = blockIdx.x;
    const int c = threadIdx.x;            // 128 threads = 2 waves
    float y = wkp1[2 * i], x = wkp1[2 * i + 1];
    float py = fminf(fmaxf(y / (float)(HIMG - 1) * (float)(HC - 1), 0.0f), (float)(HC - 1));
    float px = fminf(fmaxf(x / (float)(WIMG - 1) * (float)(WC - 1), 0.0f), (float)(WC - 1));
    int y0 = min(max((int)floorf(py), 0), HC - 2);
    int x0 = min(max((int)floorf(px), 0), WC - 2);
    float wy = py - (float)y0;
    float wx = px - (float)x0;
    const int p00 = y0 * WC + x0;
    float v00 = desc2T[(size_t)p00 * CDIM + c];
    float v01 = desc2T[(size_t)(p00 + 1) * CDIM + c];
    float v10 = desc2T[(size_t)(p00 + WC) * CDIM + c];
    float v11 = desc2T[(size_t)(p00 + WC + 1) * CDIM + c];
    float v = v00 * (1.0f - wy) * (1.0f - wx) + v01 * (1.0f - wy) * wx
            + v10 * wy * (1.0f - wx) + v11 * wy * wx;
    float a = kp1d[(size_t)i * CDIM + c];
    float s2 = v * v, sav = a * v;
    #pragma unroll
    for (int off = 32; off >= 1; off >>= 1) {
        s2  += __shfl_down(s2, off);
        sav += __shfl_down(sav, off);
    }
    __shared__ float p2[2], pav[2];
    int wave = threadIdx.x >> 6, lane = threadIdx.x & 63;
    if (lane == 0) { p2[wave] = s2; pav[wave] = sav; }
    __syncthreads();
    if (threadIdx.x == 0) {
        float nrm = sqrtf(p2[0] + p2[1]);
        float pd = (pav[0] + pav[1]) / fmaxf(nrm, 1e-12f);
        float l = fmaxf(1.0f - pd, 0.0f) * (256.0f / 3.0f);
        ploss[i] = l * INV_DENOM;
    }
}

// ---------- masked GEMM + atomic-free candidate compaction (R11) ----------
// R10 falsified launch-overhead; the addressable cost is the 134MB dots
// round-trip binding BOTH gemm (write 2.9TB/s) and select (re-read+re-bin
// 64M values, 14.5% relevant). R11: waves remapped so each wave owns 32 rows
// x ALL 128 block cols (acc[2][8]; A-frags register-resident from global --
// R6-proven; B LDS-staged exactly as R9: same 8 ds_read + 16 MFMA per kit).
// Each row's 128 values then live in one 16-lane subgroup per (mt,r), so the
// epilogue compacts candidates (>12.0, same bit test as select) with pure
// ballot+popc arithmetic -- NO atomics, NO LDS lists, fixed (nt,lrow) order
// => deterministic. Output: per (row, colblock) 96B segment [cnt | <=47
// values] in a block-contiguous 12KB chunk (exclusive ownership: no R1-style
// cross-XCD line sharing). cnt>CAP => select falls back to exact recompute.
// 50MB arena replaces 134MB write + 134MB read.
__global__ __launch_bounds__(256, 2)
void gemm_kernel(const ushort* __restrict__ A, const ushort* __restrict__ B,
                 const float* __restrict__ wkp1, const float* __restrict__ kp2,
                 ushort* __restrict__ arena) {
    __shared__ ushort sB[128 * PADK];     // 34 KB
    __shared__ float s_w[256], s_k[256];  // 2 KB coords

    const int t = threadIdx.x;
    const int bx = blockIdx.x;            // col tile 0..63
    const int by = blockIdx.y;            // row tile 0..63
    const int n0 = bx * 128;
    const int m0 = by * 128;

    s_w[t] = wkp1[2 * m0 + t];
    s_k[t] = kp2[2 * n0 + t];

    {
        const uint4* Bg = (const uint4*)(B + (size_t)n0 * CDIM);
        #pragma unroll
        for (int r = 0; r < 8; r++) {
            int g = t + 256 * r;          // uint4 index 0..2047
            int row = g >> 4;
            int k8 = g & 15;
            *(uint4*)(sB + row * PADK + k8 * 8) = Bg[g];
        }
    }

    const int lane = t & 63;
    const int wm = t >> 6;                // wave owns rows wm*32..wm*32+31
    const int lrow = lane & 15, quad = lane >> 4;
    const int qsh = quad * 16;
    const unsigned lmask = (1u << lrow) - 1u;

    // A fragments register-resident (global, L2-warm; loaded once)
    bf16x8 afr[4][2];
    #pragma unroll
    for (int kit = 0; kit < 4; kit++)
        #pragma unroll
        for (int mt = 0; mt < 2; mt++)
            afr[kit][mt] = *(const bf16x8*)(A
                + (size_t)(m0 + wm * 32 + mt * 16 + lrow) * CDIM + kit * 32 + quad * 8);

    __syncthreads();

    f32x4 acc[2][8];
    #pragma unroll
    for (int i = 0; i < 2; i++)
        #pragma unroll
        for (int j = 0; j < 8; j++) acc[i][j] = (f32x4){0.f, 0.f, 0.f, 0.f};

    #pragma unroll
    for (int kit = 0; kit < 4; kit++) {
        const int kk = kit * 32 + quad * 8;
        bf16x8 bfr[8];
        #pragma unroll
        for (int nt = 0; nt < 8; nt++)
            bfr[nt] = *(const bf16x8*)(sB + (nt * 16 + lrow) * PADK + kk);
        #pragma unroll
        for (int mt = 0; mt < 2; mt++)
            #pragma unroll
            for (int nt = 0; nt < 8; nt++)
                acc[mt][nt] = __builtin_amdgcn_mfma_f32_16x16x32_bf16(
                    afr[kit][mt], bfr[nt], acc[mt][nt], 0, 0, 0);
    }

    float ky[8], kx[8];
    #pragma unroll
    for (int nt = 0; nt < 8; nt++) {
        int jl = nt * 16 + lrow;
        ky[nt] = s_k[2 * jl]; kx[nt] = s_k[2 * jl + 1];
    }
    const float thr = 2.0f * sqrtf(32.0f) + 0.1f;
    const float thr2 = thr * thr;
    ushort* chunk = arena + (size_t)(by * 64 + bx) * 128 * SEGU;

    #pragma unroll
    for (int mt = 0; mt < 2; mt++) {
        #pragma unroll
        for (int r = 0; r < 4; r++) {
            const int il = wm * 32 + mt * 16 + quad * 4 + r;      // local row
            const float wy = s_w[2 * il], wx = s_w[2 * il + 1];
            ushort* seg = chunk + il * SEGU;
            unsigned h[8]; bool cd[8];
            #pragma unroll
            for (int nt = 0; nt < 8; nt++) {
                float dy = wy - ky[nt], dx = wx - kx[nt];
                float v = acc[mt][nt][r];
                v = (dy * dy + dx * dx <= thr2) ? v - 5.0f : v;
                h[nt] = (unsigned)f2bf(v);
                cd[nt] = (h[nt] - 0x4141u) < 0x3EBFu;     // > 12.0 (same as select)
            }
            unsigned gm[8];
            #pragma unroll
            for (int nt = 0; nt < 8; nt++)
                gm[nt] = (unsigned)(__ballot(cd[nt]) >> qsh) & 0xFFFFu;
            int base = 0;
            #pragma unroll
            for (int nt = 0; nt < 8; nt++) {
                int o = base + __popc(gm[nt] & lmask);
                if (cd[nt] && o < CAP) seg[1 + o] = (ushort)h[nt];
                base += __popc(gm[nt]);
            }
            if (lrow == 0) seg[0] = (ushort)base;          // true count (may > CAP)
        }
    }
}

// ---------- per-row top-256 hinge from candidate segments (R11) ----------
// One block per row. Each wave scans 16 segments: cnt (broadcast load) +
// lane<cnt value loads (~19/seg), one LDS atomicAdd per value into the proven
// 193-bin histogram (all entries are candidates by construction -- same bit
// domain as before, bin 192 = values > 32 with hlist exact bits). tot =
// sum(cnt) == count(>12). Then R9's suffix-scan / threshold-find / f64 sums
// verbatim (identical value set => identical results; hlist order varies but
// f64 sums of <=255 narrow-range f32 terms are exact => deterministic).
// Fallback (tot<256 | nhi>255 | cnt>CAP): exact scalar recompute from A/B
// (R7-proven, never triggers on this data).
__global__ __launch_bounds__(256)
void select_kernel(const ushort* __restrict__ arena,
                   const ushort* __restrict__ A, const ushort* __restrict__ B,
                   const float* __restrict__ wkp1, const float* __restrict__ kp2,
                   float* __restrict__ rloss) {
    const int g = blockIdx.x;                    // global row
    const int t = threadIdx.x;
    const int lane = t & 63;
    const int wave = t >> 6;
    const int by = g >> 7, rowin = g & 127;

    __shared__ unsigned hist[193];
    __shared__ unsigned hicnt;
    __shared__ ushort hlist[256];
    __shared__ int wtot[4];
    __shared__ int wovf[4];

    if (t < 193) hist[t] = 0u;
    if (t == 0) hicnt = 0u;
    __syncthreads();

    int tot_w = 0;
    bool ovf = false;
    for (int s = 0; s < 16; s++) {
        const int bx = wave * 16 + s;
        const ushort* seg = arena + ((size_t)(by * 64 + bx) * 128 + rowin) * SEGU;
        unsigned cnt = seg[0];                   // uniform broadcast load
        if (cnt > CAP) { ovf = true; cnt = 0; }  // garbage beyond cap: skip
        tot_w += (int)cnt;
        if (lane < (int)cnt) {
            unsigned h = seg[1 + lane];
            unsigned u = h - 0x4141u;            // guaranteed < 0x3EBF
            atomicAdd(&hist[min(u, 192u)], 1u);
            if (u >= 0xC0u) {                    // > 32.0: rare
                unsigned id = atomicAdd(&hicnt, 1u);
                if (id < 255u) hlist[id] = (ushort)h;
            }
        }
    }
    if (lane == 0) { wtot[wave] = tot_w; wovf[wave] = ovf ? 1 : 0; }
    __syncthreads();
    if (t >= 64) return;                          // wave0 selects; no barriers follow

    const int l = lane;
    const unsigned tot = (unsigned)(wtot[0] + wtot[1] + wtot[2] + wtot[3]);
    const bool anyovf = (wovf[0] | wovf[1] | wovf[2] | wovf[3]) != 0;

    unsigned c0 = hist[l], c1 = hist[64 + l], c2 = hist[128 + l];
    const unsigned nhi = hist[192];

    // inclusive suffix-scan across lanes for each 64-bin chunk
    unsigned s0i = c0, s1i = c1, s2i = c2;
    #pragma unroll
    for (int off = 1; off < 64; off <<= 1) {
        unsigned t0 = __shfl_down(s0i, off);
        unsigned t1 = __shfl_down(s1i, off);
        unsigned t2 = __shfl_down(s2i, off);
        if (l + off < 64) { s0i += t0; s1i += t1; s2i += t2; }
    }
    const unsigned T1 = __shfl(s1i, 0), T2 = __shfl(s2i, 0);

    const unsigned Ce0 = nhi + T1 + T2 + (s0i - c0);
    const unsigned Ce1 = nhi + T2 + (s1i - c1);
    const unsigned Ce2 = nhi + (s2i - c2);

    const bool ok = (tot >= 256u) && (nhi <= 255u) && !anyovf;

    const float thr = 2.0f * sqrtf(32.0f) + 0.1f;
    const float thr2 = thr * thr;

    unsigned ktb;            // bf16 bits of 256th-largest (attained)
    double s = 0.0;
    int cgt = 0;

    if (ok) {
        unsigned long long m0 = __ballot(Ce0 < 256u);
        unsigned long long m1 = __ballot(Ce1 < 256u);
        unsigned long long m2 = __ballot(Ce2 < 256u);
        int bmin; unsigned cg;
        if (m0) { int fl = __ffsll(m0) - 1; bmin = fl;       cg = __shfl(Ce0, fl); }
        else if (m1) { int fl = __ffsll(m1) - 1; bmin = 64 + fl;  cg = __shfl(Ce1, fl); }
        else { int fl = __ffsll(m2) - 1; bmin = 128 + fl; cg = __shfl(Ce2, fl); }
        ktb = 0x4141u + (unsigned)bmin;
        cgt = (int)cg;
        // per-bin hinge sums: cnt * (f32)(val - 0.2f), exact in f64
        if (l > bmin)       s += (double)c0 * (double)(bf2f(0x4141u + (unsigned)l) - 0.2f);
        if (64 + l > bmin)  s += (double)c1 * (double)(bf2f(0x4141u + 64u + (unsigned)l) - 0.2f);
        if (128 + l > bmin) s += (double)c2 * (double)(bf2f(0x4141u + 128u + (unsigned)l) - 0.2f);
        // values > 32.0 (all above threshold; counted inside Ce via nhi)
        for (unsigned p = (unsigned)l; p < nhi; p += 64u)
            s += (double)(bf2f(hlist[p]) - 0.2f);
        #pragma unroll
        for (int off = 32; off >= 1; off >>= 1) s += __shfl_down(s, off);
    } else {
        // ---- exact fallback: recompute the row's dots on the fly (>10 sigma)
        int lo = -1, hi = 65535;
        while (hi - lo > 1) {
            unsigned midu = (unsigned)((lo + hi) >> 1);
            int c = 0;
            for (int cc = l; cc < N2; cc += 64) {
                const ushort* ar = A + (size_t)g * CDIM;
                const ushort* br = B + (size_t)cc * CDIM;
                float av = 0.f;
                for (int k = 0; k < CDIM; k++)
                    av = fmaf(bf2f(ar[k]), bf2f(br[k]), av);
                float dy = wkp1[2 * g] - kp2[2 * cc];
                float dx = wkp1[2 * g + 1] - kp2[2 * cc + 1];
                if (dy * dy + dx * dx <= thr2) av -= 5.0f;
                c += (int)(bits2key((unsigned)f2bf(av)) > midu);
            }
            #pragma unroll
            for (int off = 32; off >= 1; off >>= 1) c += __shfl_down(c, off);
            c = __shfl(c, 0);
            if (c >= 256) lo = (int)midu; else hi = (int)midu;
        }
        unsigned kt = (unsigned)hi;
        for (int cc = l; cc < N2; cc += 64) {
            const ushort* ar = A + (size_t)g * CDIM;
            const ushort* br = B + (size_t)cc * CDIM;
            float av = 0.f;
            for (int k = 0; k < CDIM; k++)
                av = fmaf(bf2f(ar[k]), bf2f(br[k]), av);
            float dy = wkp1[2 * g] - kp2[2 * cc];
            float dx = wkp1[2 * g + 1] - kp2[2 * cc + 1];
            if (dy * dy + dx * dx <= thr2) av -= 5.0f;
            unsigned h = (unsigned)f2bf(av);
            if (bits2key(h) > kt) {
                s += (double)fmaxf(bf2f(h) - 0.2f, 0.f);
                cgt++;
            }
        }
        ktb = key2bits(kt);
        #pragma unroll
        for (int off = 32; off >= 1; off >>= 1) {
            s += __shfl_down(s, off);
            cgt += __shfl_down(cgt, off);
        }
    }

    if (l == 0) {
        float vt = bf2f(ktb);
        double S = s + (double)(256 - cgt) * (double)fmaxf(vt - 0.2f, 0.0f);
        rloss[g] = (float)(S * (double)INV_DENOM);
    }
}

// ---------- final reduce: sum 2*N1 floats -> out[0] (R9 verbatim) ----------
__global__ void reduce_kernel(const float* __restrict__ a, float* __restrict__ out) {
    const int t = threadIdx.x;
    float s = 0.f;
    for (int i = t; i < 2 * N1; i += 256) s += a[i];
    #pragma unroll
    for (int off = 32; off >= 1; off >>= 1) s += __shfl_down(s, off);
    __shared__ float ws[4];
    int wave = t >> 6, lane = t & 63;
    if (lane == 0) ws[wave] = s;
    __syncthreads();
    if (t == 0) out[0] = ws[0] + ws[1] + ws[2] + ws[3];
}

extern "C" void kernel_launch(void* const* d_in, const int* in_sizes, int n_in,
                              void* d_out, int out_size, void* d_ws, size_t ws_size,
                              hipStream_t stream) {
    const float* wkp1  = (const float*)d_in[1];
    const float* kp2   = (const float*)d_in[2];
    const float* kp1d  = (const float*)d_in[3];
    const float* kp2d  = (const float*)d_in[4];
    const float* desc2 = (const float*)d_in[5];
    float* out = (float*)d_out;

    ushort* Abf   = (ushort*)d_ws;                         // 2 MB
    ushort* Bbf   = Abf + (size_t)N1 * CDIM;               // 2 MB
    float*  loss  = (float*)(Bbf + (size_t)N2 * CDIM);     // 64 KB (pos | rows)
    float*  d2T   = loss + 2 * N1;                         // 2.4 MB
    ushort* arena = (ushort*)(d2T + (size_t)NPIX * CDIM);  // 50.3 MB segments

    int n4 = N1 * CDIM / 4;
    prep_kernel<<<(2 * n4) / 256, 256, 0, stream>>>(kp1d, kp2d, Abf, Bbf);

    tr_kernel<<<dim3(NPIX / 32, CDIM / 32), dim3(32, 8), 0, stream>>>(desc2, d2T);

    pos_kernel<<<N1, 128, 0, stream>>>(wkp1, kp1d, d2T, loss);

    dim3 grid(N2 / 128, N1 / 128);      // 64 x 64
    gemm_kernel<<<grid, 256, 0, stream>>>(Abf, Bbf, wkp1, kp2, arena);

    select_kernel<<<N1, 256, 0, stream>>>(arena, Abf, Bbf, wkp1, kp2, loss + N1);

    reduce_kernel<<<1, 256, 0, stream>>>(loss, out);
}